// Round 6
// baseline (174.843 us; speedup 1.0000x reference)
//
#include <hip/hip_runtime.h>
#include <hip/hip_bf16.h>

#define BB 2
#define TT 2048
#define CCH 1024
#define NHH 16
#define HDD 64
#define M_TOK (BB*TT)      // 4096
#define N_QKV (3*CCH)      // 3072

typedef __attribute__((ext_vector_type(8))) short bf16x8;
typedef __attribute__((ext_vector_type(4))) float f32x4;
typedef unsigned short u16;
typedef unsigned int u32;

__device__ __forceinline__ u16 f2bf(float f) {
    union { float f; u32 u; } v; v.f = f;
    u32 u = v.u;
    u32 r = (u + 0x7FFFu + ((u >> 16) & 1u)) >> 16;
    return (u16)r;
}

// pack hi16(a),hi16(b) -> u32 {b.hi<<16 | a.hi} with +0x8000 rounding
__device__ __forceinline__ u32 pk_bf16(float a, float b) {
    u32 ua = __float_as_uint(a) + 0x8000u;
    u32 ub = __float_as_uint(b) + 0x8000u;
    return __builtin_amdgcn_perm(ub, ua, 0x07060302u);
}

__device__ __forceinline__ void async_copy16(const void* g, void* l) {
    __builtin_amdgcn_global_load_lds((__attribute__((address_space(1))) void*)g,
                                     (__attribute__((address_space(3))) void*)l,
                                     16, 0, 0);
}

// ---------------- pre-pass kernels ----------------

__global__ __launch_bounds__(256) void cast_bf16_kernel(
    const float* __restrict__ src, u16* __restrict__ dst, int n4) {
    int i = blockIdx.x * 256 + threadIdx.x;
    if (i < n4) {
        float4 f = ((const float4*)src)[i];
        ushort4 o;
        o.x = f2bf(f.x); o.y = f2bf(f.y); o.z = f2bf(f.z); o.w = f2bf(f.w);
        ((ushort4*)dst)[i] = o;
    }
}

// src [R][Cn] fp32 -> dst [Cn][R] bf16; rows of dst with index < scale_rows get *= sc
__global__ __launch_bounds__(256) void transpose_bf16_kernel(
    const float* __restrict__ src, u16* __restrict__ dst, int R, int Cn,
    int scale_rows, float sc) {
    __shared__ float tile[32][33];
    int c0 = blockIdx.x * 32, r0 = blockIdx.y * 32;
    int tx = threadIdx.x, ty = threadIdx.y;
#pragma unroll
    for (int i = ty; i < 32; i += 8)
        tile[i][tx] = src[(size_t)(r0 + i) * Cn + c0 + tx];
    __syncthreads();
#pragma unroll
    for (int i = ty; i < 32; i += 8) {
        float v = tile[tx][i];
        if (c0 + i < scale_rows) v *= sc;
        dst[(size_t)(c0 + i) * R + r0 + tx] = f2bf(v);
    }
}

// ---------------- shared GEMM K-loop, BK=64, XOR-swizzled LDS ----------------

template<int SWAP, int NJ>
__device__ __forceinline__ void gemm_kloop64(
    const u16* __restrict__ A, const u16* __restrict__ Bt, int K,
    int m0, int n0, int t, u16* __restrict__ As, u16* __restrict__ Bs,
    f32x4 (&acc)[4][4])
{
    int lane = t & 63, w = t >> 6;
    int mw = (w >> 1) * 64, nw = (w & 1) * (NJ * 16);
    int mr = lane & 15, quad = lane >> 4;
    int lr = lane >> 3;                 // row-in-group 0..7
    int cswz = (lane & 7) ^ lr;         // swizzled 16B-chunk on the global side

    const u16* gA[4]; u16* lA[4];
#pragma unroll
    for (int p = 0; p < 4; ++p) {
        int grp = w * 4 + p;            // 16 groups x 8 rows = 128
        gA[p] = A + (size_t)(m0 + grp * 8 + lr) * K + cswz * 8;
        lA[p] = As + ((size_t)grp * 64 + lane) * 8;
    }
    const u16* gB[4]; u16* lB[4];
#pragma unroll
    for (int p = 0; p < NJ; ++p) {
        int grp = w * NJ + p;           // NJ groups per wave
        gB[p] = Bt + (size_t)(n0 + grp * 8 + lr) * K + cswz * 8;
        lB[p] = Bs + ((size_t)grp * 64 + lane) * 8;
    }

    int swm = mr & 7;
    for (int k0 = 0; k0 < K; k0 += 64) {
#pragma unroll
        for (int p = 0; p < 4; ++p) async_copy16(gA[p] + k0, lA[p]);
#pragma unroll
        for (int p = 0; p < NJ; ++p) async_copy16(gB[p] + k0, lB[p]);
        __syncthreads();
#pragma unroll
        for (int kk = 0; kk < 2; ++kk) {
            bf16x8 af[4], bfr[4];
#pragma unroll
            for (int i = 0; i < 4; ++i) {
                int r = mw + i * 16 + mr;
                af[i] = *(const bf16x8*)&As[r * 64 + (((kk * 4 + quad) ^ swm) << 3)];
            }
#pragma unroll
            for (int j = 0; j < NJ; ++j) {
                int r = nw + j * 16 + mr;
                bfr[j] = *(const bf16x8*)&Bs[r * 64 + (((kk * 4 + quad) ^ swm) << 3)];
            }
#pragma unroll
            for (int i = 0; i < 4; ++i)
#pragma unroll
                for (int j = 0; j < NJ; ++j) {
                    if (SWAP)
                        acc[i][j] = __builtin_amdgcn_mfma_f32_16x16x32_bf16(bfr[j], af[i], acc[i][j], 0, 0, 0);
                    else
                        acc[i][j] = __builtin_amdgcn_mfma_f32_16x16x32_bf16(af[i], bfr[j], acc[i][j], 0, 0, 0);
                }
        }
        __syncthreads();
    }
}

// ---------------- merged QKV GEMM: one 768-block dispatch ----------------

__global__ __launch_bounds__(256, 3) void qkv_gemm_kernel(
    const u16* __restrict__ A, const u16* __restrict__ Bt,
    u16* __restrict__ Qo, u16* __restrict__ Ko, u16* __restrict__ Vto)
{
    __shared__ u16 As[128 * 64];
    __shared__ u16 Bs[128 * 64];
    int t = threadIdx.x;
    int m0 = blockIdx.y * 128, n0 = blockIdx.x * 128;
    int part = n0 >> 10;
    int lane = t & 63, w = t >> 6;
    int mw = (w >> 1) * 64, nw = (w & 1) * 64;
    int mr = lane & 15, quad = lane >> 4;

    f32x4 zero = {0.f, 0.f, 0.f, 0.f};
    f32x4 acc[4][4];
#pragma unroll
    for (int i = 0; i < 4; ++i)
#pragma unroll
        for (int j = 0; j < 4; ++j) acc[i][j] = zero;

    if (part < 2) {   // block-uniform branch
        gemm_kloop64<1, 4>(A, Bt, CCH, m0, n0, t, As, Bs, acc);
        u16* dstp = part ? Ko : Qo;
#pragma unroll
        for (int i = 0; i < 4; ++i)
#pragma unroll
            for (int j = 0; j < 4; ++j) {
                int tok = m0 + mw + i * 16 + mr;
                int cg0 = n0 + nw + j * 16 + quad * 4;
                int cc = cg0 & 1023;
                int h = cc >> 6, d0 = cc & 63;
                int b = tok >> 11, tt = tok & 2047;
                int bh = b * NHH + h;
                uint2 o;
                o.x = pk_bf16(acc[i][j][0], acc[i][j][1]);
                o.y = pk_bf16(acc[i][j][2], acc[i][j][3]);
                *(uint2*)&dstp[((size_t)bh * TT + tt) * HDD + d0] = o;
            }
    } else {
        gemm_kloop64<0, 4>(A, Bt, CCH, m0, n0, t, As, Bs, acc);
#pragma unroll
        for (int i = 0; i < 4; ++i)
#pragma unroll
            for (int j = 0; j < 4; ++j) {
                int t0 = m0 + mw + i * 16 + quad * 4;
                int cg = n0 + nw + j * 16 + mr;
                int cc = cg & 1023;
                int h = cc >> 6, d = cc & 63;
                int b = t0 >> 11, tt0 = t0 & 2047;
                int bh = b * NHH + h;
                uint2 o;
                o.x = pk_bf16(acc[i][j][0], acc[i][j][1]);
                o.y = pk_bf16(acc[i][j][2], acc[i][j][3]);
                *(uint2*)&Vto[((size_t)bh * HDD + d) * TT + tt0] = o;
            }
    }
}

// ---------------- output projection: 128x64 tiles, 512 blocks (2/CU) ----------------

__global__ __launch_bounds__(256) void proj_gemm_kernel(
    const u16* __restrict__ A, const u16* __restrict__ Bt, float* __restrict__ Cout)
{
    __shared__ u16 As[128 * 64];
    __shared__ u16 Bs[64 * 64];
    int t = threadIdx.x;
    int m0 = blockIdx.y * 128, n0 = blockIdx.x * 64;
    int lane = t & 63, w = t >> 6;
    int mw = (w >> 1) * 64, nw = (w & 1) * 32;
    int mr = lane & 15, quad = lane >> 4;

    f32x4 zero = {0.f, 0.f, 0.f, 0.f};
    f32x4 acc[4][4];
#pragma unroll
    for (int i = 0; i < 4; ++i)
#pragma unroll
        for (int j = 0; j < 4; ++j) acc[i][j] = zero;

    gemm_kloop64<1, 2>(A, Bt, CCH, m0, n0, t, As, Bs, acc);

#pragma unroll
    for (int i = 0; i < 4; ++i)
#pragma unroll
        for (int j = 0; j < 2; ++j) {
            int tok = m0 + mw + i * 16 + mr;
            int cg0 = n0 + nw + j * 16 + quad * 4;
            float4 v;
            v.x = acc[i][j][0]; v.y = acc[i][j][1];
            v.z = acc[i][j][2]; v.w = acc[i][j][3];
            *(float4*)&Cout[(size_t)tok * CCH + cg0] = v;
        }
}

// ---------------- flash attention v15b: isolation round ----------------
// v15 FAILED correctness (absmax 19.9) with TWO new primitives bundled:
// (a) v_cvt_pk_bf16_f32 inline asm, (b) ones-MFMA row-sum. v15b keeps ONLY
// (b) -- provably layout-invariant (A=all-ones; same pf B-fragment the
// refcheck'd PV path uses) -- and reverts (a) to v14's pk_bf16 everywhere.
// If v15b passes: cvt_pk asm was the bug (document, never reuse).
// If v15b fails: ones-MFMA is HW-wrong (revert next round, document).
// VALU saving kept: -8 ls-adds/tile3 + epilogue shfl reduces; l is now
// summed from the SAME bf16-rounded P that PV consumes (self-consistent).

#define PST2 40   // P row stride (u16): 16B-aligned rows

template<bool MASK>
__device__ __forceinline__ void tile3(
    const u16* __restrict__ Kb, const u16* __restrict__ Vb, u16* __restrict__ pb,
    bf16x8 qf0, bf16x8 qf1, bf16x8 ones, int m, int quad, int sw, int kh,
    int kvb, int qcol, f32x4 (&o)[4], f32x4& lacc)
{
    f32x4 zero = {0.f, 0.f, 0.f, 0.f};
#pragma unroll
    for (int kc = 0; kc < 2; ++kc) {
        int rr = kh * 32 + kc * 16 + m;
        bf16x8 kf0 = *(const bf16x8*)&Kb[rr * 64 + ((quad ^ sw) << 3)];
        bf16x8 kf1 = *(const bf16x8*)&Kb[rr * 64 + (((quad + 4) ^ sw) << 3)];
        // S^T: kv = kvb + kc*16 + quad*4 + r (rows), q = qcol (cols)
        f32x4 s  = __builtin_amdgcn_mfma_f32_16x16x32_bf16(kf0, qf0, zero, 0, 0, 0);
        f32x4 st = __builtin_amdgcn_mfma_f32_16x16x32_bf16(kf1, qf1, s, 0, 0, 0);
        float e0, e1, e2, e3;
#pragma unroll
        for (int r = 0; r < 4; ++r) {
            float v = st[r];
            if (MASK && (kvb + kc * 16 + quad * 4 + r > qcol)) v = -1e30f;
            float e = __builtin_amdgcn_exp2f(v);
            if (r == 0) e0 = e; else if (r == 1) e1 = e; else if (r == 2) e2 = e; else e3 = e;
        }
        uint2 pk; pk.x = pk_bf16(e0, e1); pk.y = pk_bf16(e2, e3);
        *(uint2*)&pb[m * PST2 + kc * 16 + quad * 4] = pk;
    }
    // PV over this wave's 32-kv slice; l-row-sum rides the MFMA pipe (P.1)
    bf16x8 pf = *(const bf16x8*)&pb[m * PST2 + quad * 8];
    lacc = __builtin_amdgcn_mfma_f32_16x16x32_bf16(ones, pf, lacc, 0, 0, 0);
#pragma unroll
    for (int dg = 0; dg < 4; ++dg) {
        int rr = dg * 16 + m;
        bf16x8 vf = *(const bf16x8*)&Vb[rr * 64 + (((kh * 4 + quad) ^ sw) << 3)];
        o[dg] = __builtin_amdgcn_mfma_f32_16x16x32_bf16(vf, pf, o[dg], 0, 0, 0);
    }
}

// smem carve (u16 units): Ks dbuf [0,8192), Vs dbuf [8192,16384),
// P 8 waves x 2 tiles x 16*PST2 [16384,26624), l-exchange 128 f32 [26624,26880)
#define SM_U16 26880

__global__ __launch_bounds__(512, 2) void attn_kernel(
    const u16* __restrict__ Q, const u16* __restrict__ K,
    const u16* __restrict__ Vt, u16* __restrict__ Y)
{
    __shared__ __align__(16) u16 smem[SM_U16];
    int t = threadIdx.x;
    int w = t >> 6, lane = t & 63;
    int m = lane & 15, quad = lane >> 4;
    int iq = w >> 1, kh = w & 1;         // q-slice 0..3, kv-half 0..1

    int bid = blockIdx.x;
    int head = bid & 31;                 // head%8 = bid%8 -> XCD affinity
    int g = bid >> 5;                    // 0..15
    int pr = (g < 8) ? g : 23 - g;       // co-resident pair (bid, bid+256) sums const
    int qbA = pr;                        // light q-block (chunks 0..qbA)
    int qbB = 31 - pr;                   // heavy q-block (chunks 0..qbB)
    int rbA = qbA * 64 + iq * 16;
    int rbB = qbB * 64 + iq * 16;

    const u16* qpA = Q + ((size_t)head * TT + rbA + m) * HDD + quad * 8;
    const u16* qpB = Q + ((size_t)head * TT + rbB + m) * HDD + quad * 8;
    bf16x8 qA0 = *(const bf16x8*)qpA;
    bf16x8 qA1 = *(const bf16x8*)(qpA + 32);
    bf16x8 qB0 = *(const bf16x8*)qpB;
    bf16x8 qB1 = *(const bf16x8*)(qpB + 32);

    // bf16 1.0 = 0x3F80 in every element (A-operand for the l row-sum MFMA)
    bf16x8 ones;
#pragma unroll
    for (int i = 0; i < 8; ++i) ones[i] = (short)0x3F80;

    const u16* kbase = K + (size_t)head * TT * HDD;   // [t][d]
    const u16* vbase = Vt + (size_t)head * HDD * TT;  // [d][t]
    u16* pbA = smem + 16384 + (w * 2 + 0) * (16 * PST2);
    u16* pbB = smem + 16384 + (w * 2 + 1) * (16 * PST2);

    // staging geometry: each of 8 waves stages 8 K-rows + 8 V-rows
    int lr = lane >> 3;
    int cg = (lane & 7) ^ lr;            // XOR swizzle on global col-group
    int r0 = w * 8 + lr;                 // 0..63
    int loff = (w * 64 + lane) * 8;      // u16 offset within one 4096-u16 buffer

    f32x4 zero = {0.f, 0.f, 0.f, 0.f};
    f32x4 oA[4], oB[4], laA = zero, laB = zero;
#pragma unroll
    for (int dg = 0; dg < 4; ++dg) { oA[dg] = zero; oB[dg] = zero; }
    int qcA = rbA + m, qcB = rbB + m;
    int sw = m & 7;

    // prologue: stage chunk 0 into buffer 0
    async_copy16(kbase + (size_t)r0 * 64 + cg * 8, smem + loff);
    async_copy16(vbase + (size_t)r0 * TT + cg * 8, smem + 8192 + loff);

    for (int ic = 0; ic <= qbB; ++ic) {
        int buf = ic & 1;
        int kv0 = ic << 6;
        __syncthreads();            // chunk ic arrived; prev compute done
        if (ic < qbB) {             // prefetch chunk ic+1 into the other buffer
            int nkv = kv0 + 64;
            u16* dK = smem + (buf ^ 1) * 4096;
            u16* dV = smem + 8192 + (buf ^ 1) * 4096;
            async_copy16(kbase + (size_t)(nkv + r0) * 64 + cg * 8, dK + loff);
            async_copy16(vbase + (size_t)r0 * TT + nkv + cg * 8, dV + loff);
        }
        const u16* Kb = smem + buf * 4096;
        const u16* Vb = smem + 8192 + buf * 4096;
        int kvb = kv0 + kh * 32;
        if (ic < qbA)
            tile3<false>(Kb, Vb, pbA, qA0, qA1, ones, m, quad, sw, kh, kvb, qcA, oA, laA);
        else if (ic == qbA)
            tile3<true >(Kb, Vb, pbA, qA0, qA1, ones, m, quad, sw, kh, kvb, qcA, oA, laA);
        if (ic < qbB)
            tile3<false>(Kb, Vb, pbB, qB0, qB1, ones, m, quad, sw, kh, kvb, qcB, oB, laB);
        else
            tile3<true >(Kb, Vb, pbB, qB0, qB1, ones, m, quad, sw, kh, kvb, qcB, oB, laB);
    }

    // l_q already fully reduced over this wave's kv-half (MFMA k-reduction):
    // every lane holds l for q=lane&15 in every lacc reg.
    float lA = laA[0];
    float lB = laB[0];

    // cross-kh combine: kh=1 writes O-partials + l, kh=0 merges & stores
    __syncthreads();
    f32x4* ob = (f32x4*)smem;                 // 32KB overlay on K+V dbuf
    float* lb = (float*)&smem[26624];         // 128 floats
    if (kh) {
        f32x4* dst = ob + (size_t)iq * 512 + lane;
#pragma unroll
        for (int dg = 0; dg < 4; ++dg) {
            dst[dg * 64] = oA[dg];
            dst[(4 + dg) * 64] = oB[dg];
        }
        if (quad == 0) {
            lb[(iq * 2 + 0) * 16 + m] = lA;
            lb[(iq * 2 + 1) * 16 + m] = lB;
        }
    }
    __syncthreads();
    if (!kh) {
        f32x4* src = ob + (size_t)iq * 512 + lane;
#pragma unroll
        for (int dg = 0; dg < 4; ++dg) {
            oA[dg] += src[dg * 64];
            oB[dg] += src[(4 + dg) * 64];
        }
        lA += lb[(iq * 2 + 0) * 16 + m];
        lB += lb[(iq * 2 + 1) * 16 + m];
        float invA = 1.0f / lA, invB = 1.0f / lB;

        int b = head >> 4, h = head & 15;
        size_t roA = ((size_t)(b * TT + rbA + m)) * CCH + h * HDD;
        size_t roB = ((size_t)(b * TT + rbB + m)) * CCH + h * HDD;
#pragma unroll
        for (int dg = 0; dg < 4; ++dg) {
            uint2 ov;
            ov.x = pk_bf16(oA[dg][0] * invA, oA[dg][1] * invA);
            ov.y = pk_bf16(oA[dg][2] * invA, oA[dg][3] * invA);
            *(uint2*)&Y[roA + dg * 16 + quad * 4] = ov;
            ov.x = pk_bf16(oB[dg][0] * invB, oB[dg][1] * invB);
            ov.y = pk_bf16(oB[dg][2] * invB, oB[dg][3] * invB);
            *(uint2*)&Y[roB + dg * 16 + quad * 4] = ov;
        }
    }
}

// ---------------- launch ----------------

extern "C" void kernel_launch(void* const* d_in, const int* in_sizes, int n_in,
                              void* d_out, int out_size, void* d_ws, size_t ws_size,
                              hipStream_t stream) {
    const float* x      = (const float*)d_in[0];
    const float* w_attn = (const float*)d_in[1];
    const float* w_proj = (const float*)d_in[2];
    float* out = (float*)d_out;

    char* ws = (char*)d_ws;
    u16* x_bf   = (u16*)ws; ws += (size_t)M_TOK * CCH * 2;         // 8 MB
    u16* wqkvT  = (u16*)ws; ws += (size_t)N_QKV * CCH * 2;         // 6 MB
    u16* wprojT = (u16*)ws; ws += (size_t)CCH * CCH * 2;           // 2 MB
    u16* qbuf   = (u16*)ws; ws += (size_t)BB * NHH * TT * HDD * 2; // 8 MB
    u16* kbuf   = (u16*)ws; ws += (size_t)BB * NHH * TT * HDD * 2; // 8 MB
    u16* vtb    = (u16*)ws; ws += (size_t)BB * NHH * HDD * TT * 2; // 8 MB
    u16* yb     = (u16*)ws; ws += (size_t)M_TOK * CCH * 2;         // 8 MB

    // softmax scale * log2(e), folded into Q columns of w_attn during transpose
    const float QSC = 0.125f * 1.44269504088896f;

    // 1. cast x -> bf16
    cast_bf16_kernel<<<dim3(M_TOK * CCH / 4 / 256), dim3(256), 0, stream>>>(x, x_bf, M_TOK * CCH / 4);
    // 2. transpose weights -> bf16 [N][K]
    transpose_bf16_kernel<<<dim3(N_QKV / 32, CCH / 32), dim3(32, 8), 0, stream>>>(
        w_attn, wqkvT, CCH, N_QKV, CCH, QSC);
    transpose_bf16_kernel<<<dim3(CCH / 32, CCH / 32), dim3(32, 8), 0, stream>>>(
        w_proj, wprojT, CCH, CCH, 0, 1.0f);
    // 3. merged QKV GEMM: 768 blocks (3/CU), BK=64, swizzled LDS
    qkv_gemm_kernel<<<dim3(24, 32), dim3(256), 0, stream>>>(
        x_bf, wqkvT, qbuf, kbuf, vtb);
    // 4. flash attention v15b (ones-MFMA row-sum only; cvt_pk asm removed)
    attn_kernel<<<dim3(512), dim3(512), 0, stream>>>(qbuf, kbuf, vtb, yb);
    // 5. output projection: 128x64 tiles, BK=64, 512 blocks (2/CU)
    proj_gemm_kernel<<<dim3(16, 32), dim3(256), 0, stream>>>(yb, wprojT, out);
}

// Round 7
// 165.987 us; speedup vs baseline: 1.0534x; 1.0534x over previous
//
#include <hip/hip_runtime.h>
#include <hip/hip_bf16.h>

#define BB 2
#define TT 2048
#define CCH 1024
#define NHH 16
#define HDD 64
#define M_TOK (BB*TT)      // 4096
#define N_QKV (3*CCH)      // 3072

typedef __attribute__((ext_vector_type(8))) short bf16x8;
typedef __attribute__((ext_vector_type(4))) float f32x4;
typedef unsigned short u16;
typedef unsigned int u32;

__device__ __forceinline__ u16 f2bf(float f) {
    union { float f; u32 u; } v; v.f = f;
    u32 u = v.u;
    u32 r = (u + 0x7FFFu + ((u >> 16) & 1u)) >> 16;
    return (u16)r;
}

// pack hi16(a),hi16(b) -> u32 {b.hi<<16 | a.hi} with +0x8000 rounding
__device__ __forceinline__ u32 pk_bf16(float a, float b) {
    u32 ua = __float_as_uint(a) + 0x8000u;
    u32 ub = __float_as_uint(b) + 0x8000u;
    return __builtin_amdgcn_perm(ub, ua, 0x07060302u);
}

__device__ __forceinline__ void async_copy16(const void* g, void* l) {
    __builtin_amdgcn_global_load_lds((__attribute__((address_space(1))) void*)g,
                                     (__attribute__((address_space(3))) void*)l,
                                     16, 0, 0);
}

// ---------------- pre-pass kernels ----------------

__global__ __launch_bounds__(256) void cast_bf16_kernel(
    const float* __restrict__ src, u16* __restrict__ dst, int n4) {
    int i = blockIdx.x * 256 + threadIdx.x;
    if (i < n4) {
        float4 f = ((const float4*)src)[i];
        ushort4 o;
        o.x = f2bf(f.x); o.y = f2bf(f.y); o.z = f2bf(f.z); o.w = f2bf(f.w);
        ((ushort4*)dst)[i] = o;
    }
}

// src [R][Cn] fp32 -> dst [Cn][R] bf16; rows of dst with index < scale_rows get *= sc
__global__ __launch_bounds__(256) void transpose_bf16_kernel(
    const float* __restrict__ src, u16* __restrict__ dst, int R, int Cn,
    int scale_rows, float sc) {
    __shared__ float tile[32][33];
    int c0 = blockIdx.x * 32, r0 = blockIdx.y * 32;
    int tx = threadIdx.x, ty = threadIdx.y;
#pragma unroll
    for (int i = ty; i < 32; i += 8)
        tile[i][tx] = src[(size_t)(r0 + i) * Cn + c0 + tx];
    __syncthreads();
#pragma unroll
    for (int i = ty; i < 32; i += 8) {
        float v = tile[tx][i];
        if (c0 + i < scale_rows) v *= sc;
        dst[(size_t)(c0 + i) * R + r0 + tx] = f2bf(v);
    }
}

// ---------------- shared GEMM K-loop (proj only now), BK=64, XOR-swizzled LDS ----------------

template<int SWAP, int NJ>
__device__ __forceinline__ void gemm_kloop64(
    const u16* __restrict__ A, const u16* __restrict__ Bt, int K,
    int m0, int n0, int t, u16* __restrict__ As, u16* __restrict__ Bs,
    f32x4 (&acc)[4][4])
{
    int lane = t & 63, w = t >> 6;
    int mw = (w >> 1) * 64, nw = (w & 1) * (NJ * 16);
    int mr = lane & 15, quad = lane >> 4;
    int lr = lane >> 3;                 // row-in-group 0..7
    int cswz = (lane & 7) ^ lr;         // swizzled 16B-chunk on the global side

    const u16* gA[4]; u16* lA[4];
#pragma unroll
    for (int p = 0; p < 4; ++p) {
        int grp = w * 4 + p;            // 16 groups x 8 rows = 128
        gA[p] = A + (size_t)(m0 + grp * 8 + lr) * K + cswz * 8;
        lA[p] = As + ((size_t)grp * 64 + lane) * 8;
    }
    const u16* gB[4]; u16* lB[4];
#pragma unroll
    for (int p = 0; p < NJ; ++p) {
        int grp = w * NJ + p;           // NJ groups per wave
        gB[p] = Bt + (size_t)(n0 + grp * 8 + lr) * K + cswz * 8;
        lB[p] = Bs + ((size_t)grp * 64 + lane) * 8;
    }

    int swm = mr & 7;
    for (int k0 = 0; k0 < K; k0 += 64) {
#pragma unroll
        for (int p = 0; p < 4; ++p) async_copy16(gA[p] + k0, lA[p]);
#pragma unroll
        for (int p = 0; p < NJ; ++p) async_copy16(gB[p] + k0, lB[p]);
        __syncthreads();
#pragma unroll
        for (int kk = 0; kk < 2; ++kk) {
            bf16x8 af[4], bfr[4];
#pragma unroll
            for (int i = 0; i < 4; ++i) {
                int r = mw + i * 16 + mr;
                af[i] = *(const bf16x8*)&As[r * 64 + (((kk * 4 + quad) ^ swm) << 3)];
            }
#pragma unroll
            for (int j = 0; j < NJ; ++j) {
                int r = nw + j * 16 + mr;
                bfr[j] = *(const bf16x8*)&Bs[r * 64 + (((kk * 4 + quad) ^ swm) << 3)];
            }
#pragma unroll
            for (int i = 0; i < 4; ++i)
#pragma unroll
                for (int j = 0; j < NJ; ++j) {
                    if (SWAP)
                        acc[i][j] = __builtin_amdgcn_mfma_f32_16x16x32_bf16(bfr[j], af[i], acc[i][j], 0, 0, 0);
                    else
                        acc[i][j] = __builtin_amdgcn_mfma_f32_16x16x32_bf16(af[i], bfr[j], acc[i][j], 0, 0, 0);
                }
        }
        __syncthreads();
    }
}

// ---------------- QKV GEMM v2: 256x192 tiles, counted-vmcnt pipeline ----------------
// Theory (R6): qkv was the largest untouched kernel (~32-40us est), running the
// m97-class structure whose per-K-step vmcnt(0)-drain is the known ~900TF ceiling.
// This kernel applies the guide's T4 (counted vmcnt across RAW barriers):
//   - grid 16x16 = 256 blocks = exactly 1/CU, 512 threads, 8 waves (4M x 2N),
//     per-wave 64x96 output (4x6 16x16 frags, 96 acc VGPRs; cap 256 at 2 w/SIMD).
//   - LDS: double-buffered A(256x64) + B(192x64) = 112KB (dynamic shared).
//   - 2-deep prefetch: tiles k and k+1 in flight; per iter: vmcnt(7) [own tile-k
//     loads retired] -> s_barrier [all waves' tile-k retired] -> ds_read frags ->
//     MFMA kk0 -> lgkmcnt(0)+sched_barrier [all reads retired, rule #18] ->
//     s_barrier [WAR fence] -> stage tile k+2 into buf k&1 -> MFMA kk1.
//   - last iter waits vmcnt(0) (only 7 outstanding -> vmcnt(7) would be a no-op).
// Output: SWAP=1 for ALL columns (acc = C^T frag: token on lane&15, cols on regs).
// Q/K frags: uint2 stores along d (as before). V frags (cols >= 2048): 4 scalar
// u16 stores into Vt[d][t] (16-col frags never straddle the 1024-aligned part
// boundary, so the part branch is wave-uniform per fragment).

#define QKV_NK 16            // K / 64
#define QKV_AS_HALF 16384    // 256*64 u16
#define QKV_BS_HALF 12288    // 192*64 u16
#define QKV_SMEM_BYTES ((2*QKV_AS_HALF + 2*QKV_BS_HALF) * 2)   // 114688

__global__ __launch_bounds__(512, 1) void qkv_gemm_kernel(
    const u16* __restrict__ A, const u16* __restrict__ Bt,
    u16* __restrict__ Qo, u16* __restrict__ Ko, u16* __restrict__ Vto)
{
    extern __shared__ __align__(16) u16 smem[];
    u16* AsB = smem;                       // 2 x 256*64
    u16* BsB = smem + 2 * QKV_AS_HALF;     // 2 x 192*64
    int t = threadIdx.x;
    int lane = t & 63, w = t >> 6;
    int m0 = blockIdx.y * 256, n0 = blockIdx.x * 192;
    int mw = (w >> 1) * 64, nw = (w & 1) * 96;
    int mr = lane & 15, quad = lane >> 4, swm = mr & 7;

    f32x4 zero = {0.f, 0.f, 0.f, 0.f};
    f32x4 acc[4][6];
#pragma unroll
    for (int i = 0; i < 4; ++i)
#pragma unroll
        for (int j = 0; j < 6; ++j) acc[i][j] = zero;

    // staging geometry (verified pattern: 8 lanes/row, chunk c stored at c^(row&7))
    int lr = lane >> 3;
    int cswz = (lane & 7) ^ lr;
    const u16* gA[4]; int lAo[4];
#pragma unroll
    for (int p = 0; p < 4; ++p) {
        int grp = w * 4 + p;               // 32 groups x 8 rows = 256
        gA[p] = A + (size_t)(m0 + grp * 8 + lr) * CCH + cswz * 8;
        lAo[p] = (grp * 64 + lane) * 8;
    }
    const u16* gB[3]; int lBo[3];
#pragma unroll
    for (int p = 0; p < 3; ++p) {
        int grp = w * 3 + p;               // 24 groups x 8 rows = 192
        gB[p] = Bt + (size_t)(n0 + grp * 8 + lr) * CCH + cswz * 8;
        lBo[p] = (grp * 64 + lane) * 8;
    }

#define QKV_STAGE(K0, BUF) do {                                               \
    u16* dA_ = AsB + (BUF) * QKV_AS_HALF;                                     \
    u16* dB_ = BsB + (BUF) * QKV_BS_HALF;                                     \
    _Pragma("unroll") for (int p_ = 0; p_ < 4; ++p_)                          \
        async_copy16(gA[p_] + (K0), dA_ + lAo[p_]);                           \
    _Pragma("unroll") for (int p_ = 0; p_ < 3; ++p_)                          \
        async_copy16(gB[p_] + (K0), dB_ + lBo[p_]);                           \
  } while (0)

    // prologue: tiles 0 and 1 in flight (14 loads outstanding)
    QKV_STAGE(0, 0);
    QKV_STAGE(64, 1);

    for (int k = 0; k < QKV_NK; ++k) {
        int cur = k & 1;
        // own tile-k loads retired (7 newer may stay in flight); last iter has
        // only 7 outstanding total, so it must drain to 0.
        if (k == QKV_NK - 1) asm volatile("s_waitcnt vmcnt(0)" ::: "memory");
        else                 asm volatile("s_waitcnt vmcnt(7)" ::: "memory");
        __builtin_amdgcn_s_barrier();      // all waves: tile k fully staged
        asm volatile("" ::: "memory");
        const u16* Ac = AsB + cur * QKV_AS_HALF;
        const u16* Bc = BsB + cur * QKV_BS_HALF;
        bf16x8 a0[4], a1[4], b0[6], b1[6];
#pragma unroll
        for (int i = 0; i < 4; ++i) {
            int r = (mw + i * 16 + mr) * 64;
            a0[i] = *(const bf16x8*)&Ac[r + ((quad ^ swm) << 3)];
            a1[i] = *(const bf16x8*)&Ac[r + (((quad + 4) ^ swm) << 3)];
        }
#pragma unroll
        for (int j = 0; j < 6; ++j) {
            int r = (nw + j * 16 + mr) * 64;
            b0[j] = *(const bf16x8*)&Bc[r + ((quad ^ swm) << 3)];
            b1[j] = *(const bf16x8*)&Bc[r + (((quad + 4) ^ swm) << 3)];
        }
        // kk0 MFMAs (compiler inserts precise lgkm waits for a0/b0)
#pragma unroll
        for (int i = 0; i < 4; ++i)
#pragma unroll
            for (int j = 0; j < 6; ++j)
                acc[i][j] = __builtin_amdgcn_mfma_f32_16x16x32_bf16(b0[j], a0[i], acc[i][j], 0, 0, 0);
        // all 20 ds_reads retired before the WAR fence (rule #18 compliant)
        asm volatile("s_waitcnt lgkmcnt(0)" ::: "memory");
        __builtin_amdgcn_sched_barrier(0);
        __builtin_amdgcn_s_barrier();      // all waves done reading buf cur
        asm volatile("" ::: "memory");
        if (k < QKV_NK - 2) QKV_STAGE((k + 2) * 64, cur);  // overwrite is WAR-safe
        // kk1 MFMAs overlap the staging flight
#pragma unroll
        for (int i = 0; i < 4; ++i)
#pragma unroll
            for (int j = 0; j < 6; ++j)
                acc[i][j] = __builtin_amdgcn_mfma_f32_16x16x32_bf16(b1[j], a1[i], acc[i][j], 0, 0, 0);
    }
#undef QKV_STAGE

    // epilogue: C^T fragments; part decided per 16-col fragment (wave-uniform)
#pragma unroll
    for (int i = 0; i < 4; ++i)
#pragma unroll
        for (int j = 0; j < 6; ++j) {
            int tok = m0 + mw + i * 16 + mr;
            int cg0 = n0 + nw + j * 16 + quad * 4;
            int part = cg0 >> 10;
            int cc = cg0 & 1023;
            int h = cc >> 6, d0 = cc & 63;
            int b = tok >> 11, tt = tok & 2047;
            int bh = b * NHH + h;
            if (part < 2) {
                u16* dstp = part ? Ko : Qo;
                uint2 o;
                o.x = pk_bf16(acc[i][j][0], acc[i][j][1]);
                o.y = pk_bf16(acc[i][j][2], acc[i][j][3]);
                *(uint2*)&dstp[((size_t)bh * TT + tt) * HDD + d0] = o;
            } else {
#pragma unroll
                for (int r = 0; r < 4; ++r)
                    Vto[((size_t)bh * HDD + d0 + r) * TT + tt] = f2bf(acc[i][j][r]);
            }
        }
}

// ---------------- output projection: 128x64 tiles, 512 blocks (2/CU) ----------------

__global__ __launch_bounds__(256) void proj_gemm_kernel(
    const u16* __restrict__ A, const u16* __restrict__ Bt, float* __restrict__ Cout)
{
    __shared__ u16 As[128 * 64];
    __shared__ u16 Bs[64 * 64];
    int t = threadIdx.x;
    int m0 = blockIdx.y * 128, n0 = blockIdx.x * 64;
    int lane = t & 63, w = t >> 6;
    int mw = (w >> 1) * 64, nw = (w & 1) * 32;
    int mr = lane & 15, quad = lane >> 4;

    f32x4 zero = {0.f, 0.f, 0.f, 0.f};
    f32x4 acc[4][4];
#pragma unroll
    for (int i = 0; i < 4; ++i)
#pragma unroll
        for (int j = 0; j < 4; ++j) acc[i][j] = zero;

    gemm_kloop64<1, 2>(A, Bt, CCH, m0, n0, t, As, Bs, acc);

#pragma unroll
    for (int i = 0; i < 4; ++i)
#pragma unroll
        for (int j = 0; j < 2; ++j) {
            int tok = m0 + mw + i * 16 + mr;
            int cg0 = n0 + nw + j * 16 + quad * 4;
            float4 v;
            v.x = acc[i][j][0]; v.y = acc[i][j][1];
            v.z = acc[i][j][2]; v.w = acc[i][j][3];
            *(float4*)&Cout[(size_t)tok * CCH + cg0] = v;
        }
}

// ---------------- flash attention v15b (unchanged, passed R6) ----------------

#define PST2 40   // P row stride (u16): 16B-aligned rows

template<bool MASK>
__device__ __forceinline__ void tile3(
    const u16* __restrict__ Kb, const u16* __restrict__ Vb, u16* __restrict__ pb,
    bf16x8 qf0, bf16x8 qf1, bf16x8 ones, int m, int quad, int sw, int kh,
    int kvb, int qcol, f32x4 (&o)[4], f32x4& lacc)
{
    f32x4 zero = {0.f, 0.f, 0.f, 0.f};
#pragma unroll
    for (int kc = 0; kc < 2; ++kc) {
        int rr = kh * 32 + kc * 16 + m;
        bf16x8 kf0 = *(const bf16x8*)&Kb[rr * 64 + ((quad ^ sw) << 3)];
        bf16x8 kf1 = *(const bf16x8*)&Kb[rr * 64 + (((quad + 4) ^ sw) << 3)];
        // S^T: kv = kvb + kc*16 + quad*4 + r (rows), q = qcol (cols)
        f32x4 s  = __builtin_amdgcn_mfma_f32_16x16x32_bf16(kf0, qf0, zero, 0, 0, 0);
        f32x4 st = __builtin_amdgcn_mfma_f32_16x16x32_bf16(kf1, qf1, s, 0, 0, 0);
        float e0, e1, e2, e3;
#pragma unroll
        for (int r = 0; r < 4; ++r) {
            float v = st[r];
            if (MASK && (kvb + kc * 16 + quad * 4 + r > qcol)) v = -1e30f;
            float e = __builtin_amdgcn_exp2f(v);
            if (r == 0) e0 = e; else if (r == 1) e1 = e; else if (r == 2) e2 = e; else e3 = e;
        }
        uint2 pk; pk.x = pk_bf16(e0, e1); pk.y = pk_bf16(e2, e3);
        *(uint2*)&pb[m * PST2 + kc * 16 + quad * 4] = pk;
    }
    // PV over this wave's 32-kv slice; l-row-sum rides the MFMA pipe (P.1)
    bf16x8 pf = *(const bf16x8*)&pb[m * PST2 + quad * 8];
    lacc = __builtin_amdgcn_mfma_f32_16x16x32_bf16(ones, pf, lacc, 0, 0, 0);
#pragma unroll
    for (int dg = 0; dg < 4; ++dg) {
        int rr = dg * 16 + m;
        bf16x8 vf = *(const bf16x8*)&Vb[rr * 64 + (((kh * 4 + quad) ^ sw) << 3)];
        o[dg] = __builtin_amdgcn_mfma_f32_16x16x32_bf16(vf, pf, o[dg], 0, 0, 0);
    }
}

// smem carve (u16 units): Ks dbuf [0,8192), Vs dbuf [8192,16384),
// P 8 waves x 2 tiles x 16*PST2 [16384,26624), l-exchange 128 f32 [26624,26880)
#define SM_U16 26880

__global__ __launch_bounds__(512, 2) void attn_kernel(
    const u16* __restrict__ Q, const u16* __restrict__ K,
    const u16* __restrict__ Vt, u16* __restrict__ Y)
{
    __shared__ __align__(16) u16 smem[SM_U16];
    int t = threadIdx.x;
    int w = t >> 6, lane = t & 63;
    int m = lane & 15, quad = lane >> 4;
    int iq = w >> 1, kh = w & 1;         // q-slice 0..3, kv-half 0..1

    int bid = blockIdx.x;
    int head = bid & 31;                 // head%8 = bid%8 -> XCD affinity
    int g = bid >> 5;                    // 0..15
    int pr = (g < 8) ? g : 23 - g;       // co-resident pair (bid, bid+256) sums const
    int qbA = pr;                        // light q-block (chunks 0..qbA)
    int qbB = 31 - pr;                   // heavy q-block (chunks 0..qbB)
    int rbA = qbA * 64 + iq * 16;
    int rbB = qbB * 64 + iq * 16;

    const u16* qpA = Q + ((size_t)head * TT + rbA + m) * HDD + quad * 8;
    const u16* qpB = Q + ((size_t)head * TT + rbB + m) * HDD + quad * 8;
    bf16x8 qA0 = *(const bf16x8*)qpA;
    bf16x8 qA1 = *(const bf16x8*)(qpA + 32);
    bf16x8 qB0 = *(const bf16x8*)qpB;
    bf16x8 qB1 = *(const bf16x8*)(qpB + 32);

    // bf16 1.0 = 0x3F80 in every element (A-operand for the l row-sum MFMA)
    bf16x8 ones;
#pragma unroll
    for (int i = 0; i < 8; ++i) ones[i] = (short)0x3F80;

    const u16* kbase = K + (size_t)head * TT * HDD;   // [t][d]
    const u16* vbase = Vt + (size_t)head * HDD * TT;  // [d][t]
    u16* pbA = smem + 16384 + (w * 2 + 0) * (16 * PST2);
    u16* pbB = smem + 16384 + (w * 2 + 1) * (16 * PST2);

    // staging geometry: each of 8 waves stages 8 K-rows + 8 V-rows
    int lr = lane >> 3;
    int cg = (lane & 7) ^ lr;            // XOR swizzle on global col-group
    int r0 = w * 8 + lr;                 // 0..63
    int loff = (w * 64 + lane) * 8;      // u16 offset within one 4096-u16 buffer

    f32x4 zero = {0.f, 0.f, 0.f, 0.f};
    f32x4 oA[4], oB[4], laA = zero, laB = zero;
#pragma unroll
    for (int dg = 0; dg < 4; ++dg) { oA[dg] = zero; oB[dg] = zero; }
    int qcA = rbA + m, qcB = rbB + m;
    int sw = m & 7;

    // prologue: stage chunk 0 into buffer 0
    async_copy16(kbase + (size_t)r0 * 64 + cg * 8, smem + loff);
    async_copy16(vbase + (size_t)r0 * TT + cg * 8, smem + 8192 + loff);

    for (int ic = 0; ic <= qbB; ++ic) {
        int buf = ic & 1;
        int kv0 = ic << 6;
        __syncthreads();            // chunk ic arrived; prev compute done
        if (ic < qbB) {             // prefetch chunk ic+1 into the other buffer
            int nkv = kv0 + 64;
            u16* dK = smem + (buf ^ 1) * 4096;
            u16* dV = smem + 8192 + (buf ^ 1) * 4096;
            async_copy16(kbase + (size_t)(nkv + r0) * 64 + cg * 8, dK + loff);
            async_copy16(vbase + (size_t)r0 * TT + nkv + cg * 8, dV + loff);
        }
        const u16* Kb = smem + buf * 4096;
        const u16* Vb = smem + 8192 + buf * 4096;
        int kvb = kv0 + kh * 32;
        if (ic < qbA)
            tile3<false>(Kb, Vb, pbA, qA0, qA1, ones, m, quad, sw, kh, kvb, qcA, oA, laA);
        else if (ic == qbA)
            tile3<true >(Kb, Vb, pbA, qA0, qA1, ones, m, quad, sw, kh, kvb, qcA, oA, laA);
        if (ic < qbB)
            tile3<false>(Kb, Vb, pbB, qB0, qB1, ones, m, quad, sw, kh, kvb, qcB, oB, laB);
        else
            tile3<true >(Kb, Vb, pbB, qB0, qB1, ones, m, quad, sw, kh, kvb, qcB, oB, laB);
    }

    // l_q already fully reduced over this wave's kv-half (MFMA k-reduction):
    // every lane holds l for q=lane&15 in every lacc reg.
    float lA = laA[0];
    float lB = laB[0];

    // cross-kh combine: kh=1 writes O-partials + l, kh=0 merges & stores
    __syncthreads();
    f32x4* ob = (f32x4*)smem;                 // 32KB overlay on K+V dbuf
    float* lb = (float*)&smem[26624];         // 128 floats
    if (kh) {
        f32x4* dst = ob + (size_t)iq * 512 + lane;
#pragma unroll
        for (int dg = 0; dg < 4; ++dg) {
            dst[dg * 64] = oA[dg];
            dst[(4 + dg) * 64] = oB[dg];
        }
        if (quad == 0) {
            lb[(iq * 2 + 0) * 16 + m] = lA;
            lb[(iq * 2 + 1) * 16 + m] = lB;
        }
    }
    __syncthreads();
    if (!kh) {
        f32x4* src = ob + (size_t)iq * 512 + lane;
#pragma unroll
        for (int dg = 0; dg < 4; ++dg) {
            oA[dg] += src[dg * 64];
            oB[dg] += src[(4 + dg) * 64];
        }
        lA += lb[(iq * 2 + 0) * 16 + m];
        lB += lb[(iq * 2 + 1) * 16 + m];
        float invA = 1.0f / lA, invB = 1.0f / lB;

        int b = head >> 4, h = head & 15;
        size_t roA = ((size_t)(b * TT + rbA + m)) * CCH + h * HDD;
        size_t roB = ((size_t)(b * TT + rbB + m)) * CCH + h * HDD;
#pragma unroll
        for (int dg = 0; dg < 4; ++dg) {
            uint2 ov;
            ov.x = pk_bf16(oA[dg][0] * invA, oA[dg][1] * invA);
            ov.y = pk_bf16(oA[dg][2] * invA, oA[dg][3] * invA);
            *(uint2*)&Y[roA + dg * 16 + quad * 4] = ov;
            ov.x = pk_bf16(oB[dg][0] * invB, oB[dg][1] * invB);
            ov.y = pk_bf16(oB[dg][2] * invB, oB[dg][3] * invB);
            *(uint2*)&Y[roB + dg * 16 + quad * 4] = ov;
        }
    }
}

// ---------------- launch ----------------

extern "C" void kernel_launch(void* const* d_in, const int* in_sizes, int n_in,
                              void* d_out, int out_size, void* d_ws, size_t ws_size,
                              hipStream_t stream) {
    const float* x      = (const float*)d_in[0];
    const float* w_attn = (const float*)d_in[1];
    const float* w_proj = (const float*)d_in[2];
    float* out = (float*)d_out;

    char* ws = (char*)d_ws;
    u16* x_bf   = (u16*)ws; ws += (size_t)M_TOK * CCH * 2;         // 8 MB
    u16* wqkvT  = (u16*)ws; ws += (size_t)N_QKV * CCH * 2;         // 6 MB
    u16* wprojT = (u16*)ws; ws += (size_t)CCH * CCH * 2;           // 2 MB
    u16* qbuf   = (u16*)ws; ws += (size_t)BB * NHH * TT * HDD * 2; // 8 MB
    u16* kbuf   = (u16*)ws; ws += (size_t)BB * NHH * TT * HDD * 2; // 8 MB
    u16* vtb    = (u16*)ws; ws += (size_t)BB * NHH * HDD * TT * 2; // 8 MB
    u16* yb     = (u16*)ws; ws += (size_t)M_TOK * CCH * 2;         // 8 MB

    // one-time: allow 112KB dynamic LDS for the qkv kernel (host-side, not captured)
    static bool attr_done = false;
    if (!attr_done) {
        (void)hipFuncSetAttribute(reinterpret_cast<const void*>(qkv_gemm_kernel),
                                  hipFuncAttributeMaxDynamicSharedMemorySize,
                                  QKV_SMEM_BYTES);
        attr_done = true;
    }

    // softmax scale * log2(e), folded into Q columns of w_attn during transpose
    const float QSC = 0.125f * 1.44269504088896f;

    // 1. cast x -> bf16
    cast_bf16_kernel<<<dim3(M_TOK * CCH / 4 / 256), dim3(256), 0, stream>>>(x, x_bf, M_TOK * CCH / 4);
    // 2. transpose weights -> bf16 [N][K]
    transpose_bf16_kernel<<<dim3(N_QKV / 32, CCH / 32), dim3(32, 8), 0, stream>>>(
        w_attn, wqkvT, CCH, N_QKV, CCH, QSC);
    transpose_bf16_kernel<<<dim3(CCH / 32, CCH / 32), dim3(32, 8), 0, stream>>>(
        w_proj, wprojT, CCH, CCH, 0, 1.0f);
    // 3. QKV GEMM v2: 256 blocks (1/CU), 256x192 tiles, counted-vmcnt pipeline
    qkv_gemm_kernel<<<dim3(16, 16), dim3(512), QKV_SMEM_BYTES, stream>>>(
        x_bf, wqkvT, qbuf, kbuf, vtb);
    // 4. flash attention v15b (unchanged)
    attn_kernel<<<dim3(512), dim3(512), 0, stream>>>(qbuf, kbuf, vtb, yb);
    // 5. output projection: 128x64 tiles, BK=64, 512 blocks (2/CU)
    proj_gemm_kernel<<<dim3(16, 32), dim3(256), 0, stream>>>(yb, wprojT, out);
}

// Round 8
// 162.905 us; speedup vs baseline: 1.0733x; 1.0189x over previous
//
#include <hip/hip_runtime.h>
#include <hip/hip_bf16.h>

#define BB 2
#define TT 2048
#define CCH 1024
#define NHH 16
#define HDD 64
#define M_TOK (BB*TT)      // 4096
#define N_QKV (3*CCH)      // 3072

typedef __attribute__((ext_vector_type(8))) short bf16x8;
typedef __attribute__((ext_vector_type(4))) float f32x4;
typedef unsigned short u16;
typedef unsigned int u32;

__device__ __forceinline__ u16 f2bf(float f) {
    union { float f; u32 u; } v; v.f = f;
    u32 u = v.u;
    u32 r = (u + 0x7FFFu + ((u >> 16) & 1u)) >> 16;
    return (u16)r;
}

// pack hi16(a),hi16(b) -> u32 {b.hi<<16 | a.hi} with +0x8000 rounding
__device__ __forceinline__ u32 pk_bf16(float a, float b) {
    u32 ua = __float_as_uint(a) + 0x8000u;
    u32 ub = __float_as_uint(b) + 0x8000u;
    return __builtin_amdgcn_perm(ub, ua, 0x07060302u);
}

__device__ __forceinline__ void async_copy16(const void* g, void* l) {
    __builtin_amdgcn_global_load_lds((__attribute__((address_space(1))) void*)g,
                                     (__attribute__((address_space(3))) void*)l,
                                     16, 0, 0);
}

// ---------------- pre-pass kernels ----------------

__global__ __launch_bounds__(256) void cast_bf16_kernel(
    const float* __restrict__ src, u16* __restrict__ dst, int n4) {
    int i = blockIdx.x * 256 + threadIdx.x;
    if (i < n4) {
        float4 f = ((const float4*)src)[i];
        ushort4 o;
        o.x = f2bf(f.x); o.y = f2bf(f.y); o.z = f2bf(f.z); o.w = f2bf(f.w);
        ((ushort4*)dst)[i] = o;
    }
}

// src [R][Cn] fp32 -> dst [Cn][R] bf16; rows of dst with index < scale_rows get *= sc
__global__ __launch_bounds__(256) void transpose_bf16_kernel(
    const float* __restrict__ src, u16* __restrict__ dst, int R, int Cn,
    int scale_rows, float sc) {
    __shared__ float tile[32][33];
    int c0 = blockIdx.x * 32, r0 = blockIdx.y * 32;
    int tx = threadIdx.x, ty = threadIdx.y;
#pragma unroll
    for (int i = ty; i < 32; i += 8)
        tile[i][tx] = src[(size_t)(r0 + i) * Cn + c0 + tx];
    __syncthreads();
#pragma unroll
    for (int i = ty; i < 32; i += 8) {
        float v = tile[tx][i];
        if (c0 + i < scale_rows) v *= sc;
        dst[(size_t)(c0 + i) * R + r0 + tx] = f2bf(v);
    }
}

// ---------------- QKV GEMM v2: 256x192 tiles, counted-vmcnt pipeline (R7 WIN) ----------------

#define QKV_NK 16            // K / 64
#define QKV_AS_HALF 16384    // 256*64 u16
#define QKV_BS_HALF 12288    // 192*64 u16
#define QKV_SMEM_BYTES ((2*QKV_AS_HALF + 2*QKV_BS_HALF) * 2)   // 114688

__global__ __launch_bounds__(512, 1) void qkv_gemm_kernel(
    const u16* __restrict__ A, const u16* __restrict__ Bt,
    u16* __restrict__ Qo, u16* __restrict__ Ko, u16* __restrict__ Vto)
{
    extern __shared__ __align__(16) u16 smem[];
    u16* AsB = smem;                       // 2 x 256*64
    u16* BsB = smem + 2 * QKV_AS_HALF;     // 2 x 192*64
    int t = threadIdx.x;
    int lane = t & 63, w = t >> 6;
    int m0 = blockIdx.y * 256, n0 = blockIdx.x * 192;
    int mw = (w >> 1) * 64, nw = (w & 1) * 96;
    int mr = lane & 15, quad = lane >> 4, swm = mr & 7;

    f32x4 zero = {0.f, 0.f, 0.f, 0.f};
    f32x4 acc[4][6];
#pragma unroll
    for (int i = 0; i < 4; ++i)
#pragma unroll
        for (int j = 0; j < 6; ++j) acc[i][j] = zero;

    // staging geometry (verified pattern: 8 lanes/row, chunk c stored at c^(row&7))
    int lr = lane >> 3;
    int cswz = (lane & 7) ^ lr;
    const u16* gA[4]; int lAo[4];
#pragma unroll
    for (int p = 0; p < 4; ++p) {
        int grp = w * 4 + p;               // 32 groups x 8 rows = 256
        gA[p] = A + (size_t)(m0 + grp * 8 + lr) * CCH + cswz * 8;
        lAo[p] = (grp * 64 + lane) * 8;
    }
    const u16* gB[3]; int lBo[3];
#pragma unroll
    for (int p = 0; p < 3; ++p) {
        int grp = w * 3 + p;               // 24 groups x 8 rows = 192
        gB[p] = Bt + (size_t)(n0 + grp * 8 + lr) * CCH + cswz * 8;
        lBo[p] = (grp * 64 + lane) * 8;
    }

#define QKV_STAGE(K0, BUF) do {                                               \
    u16* dA_ = AsB + (BUF) * QKV_AS_HALF;                                     \
    u16* dB_ = BsB + (BUF) * QKV_BS_HALF;                                     \
    _Pragma("unroll") for (int p_ = 0; p_ < 4; ++p_)                          \
        async_copy16(gA[p_] + (K0), dA_ + lAo[p_]);                           \
    _Pragma("unroll") for (int p_ = 0; p_ < 3; ++p_)                          \
        async_copy16(gB[p_] + (K0), dB_ + lBo[p_]);                           \
  } while (0)

    // prologue: tiles 0 and 1 in flight (14 loads outstanding)
    QKV_STAGE(0, 0);
    QKV_STAGE(64, 1);

    for (int k = 0; k < QKV_NK; ++k) {
        int cur = k & 1;
        if (k == QKV_NK - 1) asm volatile("s_waitcnt vmcnt(0)" ::: "memory");
        else                 asm volatile("s_waitcnt vmcnt(7)" ::: "memory");
        __builtin_amdgcn_s_barrier();      // all waves: tile k fully staged
        asm volatile("" ::: "memory");
        const u16* Ac = AsB + cur * QKV_AS_HALF;
        const u16* Bc = BsB + cur * QKV_BS_HALF;
        bf16x8 a0[4], a1[4], b0[6], b1[6];
#pragma unroll
        for (int i = 0; i < 4; ++i) {
            int r = (mw + i * 16 + mr) * 64;
            a0[i] = *(const bf16x8*)&Ac[r + ((quad ^ swm) << 3)];
            a1[i] = *(const bf16x8*)&Ac[r + (((quad + 4) ^ swm) << 3)];
        }
#pragma unroll
        for (int j = 0; j < 6; ++j) {
            int r = (nw + j * 16 + mr) * 64;
            b0[j] = *(const bf16x8*)&Bc[r + ((quad ^ swm) << 3)];
            b1[j] = *(const bf16x8*)&Bc[r + (((quad + 4) ^ swm) << 3)];
        }
#pragma unroll
        for (int i = 0; i < 4; ++i)
#pragma unroll
            for (int j = 0; j < 6; ++j)
                acc[i][j] = __builtin_amdgcn_mfma_f32_16x16x32_bf16(b0[j], a0[i], acc[i][j], 0, 0, 0);
        asm volatile("s_waitcnt lgkmcnt(0)" ::: "memory");
        __builtin_amdgcn_sched_barrier(0);
        __builtin_amdgcn_s_barrier();      // all waves done reading buf cur
        asm volatile("" ::: "memory");
        if (k < QKV_NK - 2) QKV_STAGE((k + 2) * 64, cur);  // WAR-safe overwrite
#pragma unroll
        for (int i = 0; i < 4; ++i)
#pragma unroll
            for (int j = 0; j < 6; ++j)
                acc[i][j] = __builtin_amdgcn_mfma_f32_16x16x32_bf16(b1[j], a1[i], acc[i][j], 0, 0, 0);
    }
#undef QKV_STAGE

    // epilogue: C^T fragments; part decided per 16-col fragment (wave-uniform)
#pragma unroll
    for (int i = 0; i < 4; ++i)
#pragma unroll
        for (int j = 0; j < 6; ++j) {
            int tok = m0 + mw + i * 16 + mr;
            int cg0 = n0 + nw + j * 16 + quad * 4;
            int part = cg0 >> 10;
            int cc = cg0 & 1023;
            int h = cc >> 6, d0 = cc & 63;
            int b = tok >> 11, tt = tok & 2047;
            int bh = b * NHH + h;
            if (part < 2) {
                u16* dstp = part ? Ko : Qo;
                uint2 o;
                o.x = pk_bf16(acc[i][j][0], acc[i][j][1]);
                o.y = pk_bf16(acc[i][j][2], acc[i][j][3]);
                *(uint2*)&dstp[((size_t)bh * TT + tt) * HDD + d0] = o;
            } else {
#pragma unroll
                for (int r = 0; r < 4; ++r)
                    Vto[((size_t)bh * HDD + d0 + r) * TT + tt] = f2bf(acc[i][j][r]);
            }
        }
}

// ---------------- proj GEMM v2: 128x128 tiles, counted-vmcnt pipeline ----------------
// R8: clone of the verified qkv-v2 T4 skeleton. Grid 8x16... -> (N/128=8, M/128=32)
// = 256 blocks = 1/CU, 512 threads = 8 waves (4M x 2N), per-wave 32x64 output
// (2x4 frags, 32 acc VGPRs). Dbuf LDS 2x(128x64 A + 128x64 B) = 64KB dynamic.
// 4 loads/thread/tile -> vmcnt(4) per iter, vmcnt(0) at last. Same swizzle math.

#define PRJ_NK 16            // K / 64
#define PRJ_AS_HALF 8192     // 128*64 u16
#define PRJ_SMEM_BYTES (4 * PRJ_AS_HALF * 2)   // 65536

__global__ __launch_bounds__(512, 1) void proj_gemm_kernel(
    const u16* __restrict__ A, const u16* __restrict__ Bt, float* __restrict__ Cout)
{
    extern __shared__ __align__(16) u16 psmem[];
    u16* AsB = psmem;                      // 2 x 128*64
    u16* BsB = psmem + 2 * PRJ_AS_HALF;    // 2 x 128*64
    int t = threadIdx.x;
    int lane = t & 63, w = t >> 6;
    int m0 = blockIdx.y * 128, n0 = blockIdx.x * 128;
    int mw = (w >> 1) * 32, nw = (w & 1) * 64;
    int mr = lane & 15, quad = lane >> 4, swm = mr & 7;

    f32x4 zero = {0.f, 0.f, 0.f, 0.f};
    f32x4 acc[2][4];
#pragma unroll
    for (int i = 0; i < 2; ++i)
#pragma unroll
        for (int j = 0; j < 4; ++j) acc[i][j] = zero;

    int lr = lane >> 3;
    int cswz = (lane & 7) ^ lr;
    const u16* gA[2]; int lAo[2];
#pragma unroll
    for (int p = 0; p < 2; ++p) {
        int grp = w * 2 + p;               // 16 groups x 8 rows = 128
        gA[p] = A + (size_t)(m0 + grp * 8 + lr) * CCH + cswz * 8;
        lAo[p] = (grp * 64 + lane) * 8;
    }
    const u16* gB[2]; int lBo[2];
#pragma unroll
    for (int p = 0; p < 2; ++p) {
        int grp = w * 2 + p;               // 16 groups x 8 rows = 128
        gB[p] = Bt + (size_t)(n0 + grp * 8 + lr) * CCH + cswz * 8;
        lBo[p] = (grp * 64 + lane) * 8;
    }

#define PRJ_STAGE(K0, BUF) do {                                               \
    u16* dA_ = AsB + (BUF) * PRJ_AS_HALF;                                     \
    u16* dB_ = BsB + (BUF) * PRJ_AS_HALF;                                     \
    _Pragma("unroll") for (int p_ = 0; p_ < 2; ++p_)                          \
        async_copy16(gA[p_] + (K0), dA_ + lAo[p_]);                           \
    _Pragma("unroll") for (int p_ = 0; p_ < 2; ++p_)                          \
        async_copy16(gB[p_] + (K0), dB_ + lBo[p_]);                           \
  } while (0)

    PRJ_STAGE(0, 0);
    PRJ_STAGE(64, 1);

    for (int k = 0; k < PRJ_NK; ++k) {
        int cur = k & 1;
        if (k == PRJ_NK - 1) asm volatile("s_waitcnt vmcnt(0)" ::: "memory");
        else                 asm volatile("s_waitcnt vmcnt(4)" ::: "memory");
        __builtin_amdgcn_s_barrier();      // tile k fully staged
        asm volatile("" ::: "memory");
        const u16* Ac = AsB + cur * PRJ_AS_HALF;
        const u16* Bc = BsB + cur * PRJ_AS_HALF;
        bf16x8 a0[2], a1[2], b0[4], b1[4];
#pragma unroll
        for (int i = 0; i < 2; ++i) {
            int r = (mw + i * 16 + mr) * 64;
            a0[i] = *(const bf16x8*)&Ac[r + ((quad ^ swm) << 3)];
            a1[i] = *(const bf16x8*)&Ac[r + (((quad + 4) ^ swm) << 3)];
        }
#pragma unroll
        for (int j = 0; j < 4; ++j) {
            int r = (nw + j * 16 + mr) * 64;
            b0[j] = *(const bf16x8*)&Bc[r + ((quad ^ swm) << 3)];
            b1[j] = *(const bf16x8*)&Bc[r + (((quad + 4) ^ swm) << 3)];
        }
#pragma unroll
        for (int i = 0; i < 2; ++i)
#pragma unroll
            for (int j = 0; j < 4; ++j)
                acc[i][j] = __builtin_amdgcn_mfma_f32_16x16x32_bf16(b0[j], a0[i], acc[i][j], 0, 0, 0);
        asm volatile("s_waitcnt lgkmcnt(0)" ::: "memory");
        __builtin_amdgcn_sched_barrier(0);
        __builtin_amdgcn_s_barrier();      // all waves done reading buf cur
        asm volatile("" ::: "memory");
        if (k < PRJ_NK - 2) PRJ_STAGE((k + 2) * 64, cur);
#pragma unroll
        for (int i = 0; i < 2; ++i)
#pragma unroll
            for (int j = 0; j < 4; ++j)
                acc[i][j] = __builtin_amdgcn_mfma_f32_16x16x32_bf16(b1[j], a1[i], acc[i][j], 0, 0, 0);
    }
#undef PRJ_STAGE

    // epilogue: C^T fragments (tok on lane&15), float4 stores
#pragma unroll
    for (int i = 0; i < 2; ++i)
#pragma unroll
        for (int j = 0; j < 4; ++j) {
            int tok = m0 + mw + i * 16 + mr;
            int cg0 = n0 + nw + j * 16 + quad * 4;
            float4 v;
            v.x = acc[i][j][0]; v.y = acc[i][j][1];
            v.z = acc[i][j][2]; v.w = acc[i][j][3];
            *(float4*)&Cout[(size_t)tok * CCH + cg0] = v;
        }
}

// ---------------- flash attention v15b (unchanged, passed R6/R7) ----------------

#define PST2 40   // P row stride (u16): 16B-aligned rows

template<bool MASK>
__device__ __forceinline__ void tile3(
    const u16* __restrict__ Kb, const u16* __restrict__ Vb, u16* __restrict__ pb,
    bf16x8 qf0, bf16x8 qf1, bf16x8 ones, int m, int quad, int sw, int kh,
    int kvb, int qcol, f32x4 (&o)[4], f32x4& lacc)
{
    f32x4 zero = {0.f, 0.f, 0.f, 0.f};
#pragma unroll
    for (int kc = 0; kc < 2; ++kc) {
        int rr = kh * 32 + kc * 16 + m;
        bf16x8 kf0 = *(const bf16x8*)&Kb[rr * 64 + ((quad ^ sw) << 3)];
        bf16x8 kf1 = *(const bf16x8*)&Kb[rr * 64 + (((quad + 4) ^ sw) << 3)];
        // S^T: kv = kvb + kc*16 + quad*4 + r (rows), q = qcol (cols)
        f32x4 s  = __builtin_amdgcn_mfma_f32_16x16x32_bf16(kf0, qf0, zero, 0, 0, 0);
        f32x4 st = __builtin_amdgcn_mfma_f32_16x16x32_bf16(kf1, qf1, s, 0, 0, 0);
        float e0, e1, e2, e3;
#pragma unroll
        for (int r = 0; r < 4; ++r) {
            float v = st[r];
            if (MASK && (kvb + kc * 16 + quad * 4 + r > qcol)) v = -1e30f;
            float e = __builtin_amdgcn_exp2f(v);
            if (r == 0) e0 = e; else if (r == 1) e1 = e; else if (r == 2) e2 = e; else e3 = e;
        }
        uint2 pk; pk.x = pk_bf16(e0, e1); pk.y = pk_bf16(e2, e3);
        *(uint2*)&pb[m * PST2 + kc * 16 + quad * 4] = pk;
    }
    // PV over this wave's 32-kv slice; l-row-sum rides the MFMA pipe (P.1)
    bf16x8 pf = *(const bf16x8*)&pb[m * PST2 + quad * 8];
    lacc = __builtin_amdgcn_mfma_f32_16x16x32_bf16(ones, pf, lacc, 0, 0, 0);
#pragma unroll
    for (int dg = 0; dg < 4; ++dg) {
        int rr = dg * 16 + m;
        bf16x8 vf = *(const bf16x8*)&Vb[rr * 64 + (((kh * 4 + quad) ^ sw) << 3)];
        o[dg] = __builtin_amdgcn_mfma_f32_16x16x32_bf16(vf, pf, o[dg], 0, 0, 0);
    }
}

// smem carve (u16 units): Ks dbuf [0,8192), Vs dbuf [8192,16384),
// P 8 waves x 2 tiles x 16*PST2 [16384,26624), l-exchange 128 f32 [26624,26880)
#define SM_U16 26880

__global__ __launch_bounds__(512, 2) void attn_kernel(
    const u16* __restrict__ Q, const u16* __restrict__ K,
    const u16* __restrict__ Vt, u16* __restrict__ Y)
{
    __shared__ __align__(16) u16 smem[SM_U16];
    int t = threadIdx.x;
    int w = t >> 6, lane = t & 63;
    int m = lane & 15, quad = lane >> 4;
    int iq = w >> 1, kh = w & 1;         // q-slice 0..3, kv-half 0..1

    int bid = blockIdx.x;
    int head = bid & 31;                 // head%8 = bid%8 -> XCD affinity
    int g = bid >> 5;                    // 0..15
    int pr = (g < 8) ? g : 23 - g;       // co-resident pair (bid, bid+256) sums const
    int qbA = pr;                        // light q-block (chunks 0..qbA)
    int qbB = 31 - pr;                   // heavy q-block (chunks 0..qbB)
    int rbA = qbA * 64 + iq * 16;
    int rbB = qbB * 64 + iq * 16;

    const u16* qpA = Q + ((size_t)head * TT + rbA + m) * HDD + quad * 8;
    const u16* qpB = Q + ((size_t)head * TT + rbB + m) * HDD + quad * 8;
    bf16x8 qA0 = *(const bf16x8*)qpA;
    bf16x8 qA1 = *(const bf16x8*)(qpA + 32);
    bf16x8 qB0 = *(const bf16x8*)qpB;
    bf16x8 qB1 = *(const bf16x8*)(qpB + 32);

    // bf16 1.0 = 0x3F80 in every element (A-operand for the l row-sum MFMA)
    bf16x8 ones;
#pragma unroll
    for (int i = 0; i < 8; ++i) ones[i] = (short)0x3F80;

    const u16* kbase = K + (size_t)head * TT * HDD;   // [t][d]
    const u16* vbase = Vt + (size_t)head * HDD * TT;  // [d][t]
    u16* pbA = smem + 16384 + (w * 2 + 0) * (16 * PST2);
    u16* pbB = smem + 16384 + (w * 2 + 1) * (16 * PST2);

    // staging geometry: each of 8 waves stages 8 K-rows + 8 V-rows
    int lr = lane >> 3;
    int cg = (lane & 7) ^ lr;            // XOR swizzle on global col-group
    int r0 = w * 8 + lr;                 // 0..63
    int loff = (w * 64 + lane) * 8;      // u16 offset within one 4096-u16 buffer

    f32x4 zero = {0.f, 0.f, 0.f, 0.f};
    f32x4 oA[4], oB[4], laA = zero, laB = zero;
#pragma unroll
    for (int dg = 0; dg < 4; ++dg) { oA[dg] = zero; oB[dg] = zero; }
    int qcA = rbA + m, qcB = rbB + m;
    int sw = m & 7;

    // prologue: stage chunk 0 into buffer 0
    async_copy16(kbase + (size_t)r0 * 64 + cg * 8, smem + loff);
    async_copy16(vbase + (size_t)r0 * TT + cg * 8, smem + 8192 + loff);

    for (int ic = 0; ic <= qbB; ++ic) {
        int buf = ic & 1;
        int kv0 = ic << 6;
        __syncthreads();            // chunk ic arrived; prev compute done
        if (ic < qbB) {             // prefetch chunk ic+1 into the other buffer
            int nkv = kv0 + 64;
            u16* dK = smem + (buf ^ 1) * 4096;
            u16* dV = smem + 8192 + (buf ^ 1) * 4096;
            async_copy16(kbase + (size_t)(nkv + r0) * 64 + cg * 8, dK + loff);
            async_copy16(vbase + (size_t)r0 * TT + nkv + cg * 8, dV + loff);
        }
        const u16* Kb = smem + buf * 4096;
        const u16* Vb = smem + 8192 + buf * 4096;
        int kvb = kv0 + kh * 32;
        if (ic < qbA)
            tile3<false>(Kb, Vb, pbA, qA0, qA1, ones, m, quad, sw, kh, kvb, qcA, oA, laA);
        else if (ic == qbA)
            tile3<true >(Kb, Vb, pbA, qA0, qA1, ones, m, quad, sw, kh, kvb, qcA, oA, laA);
        if (ic < qbB)
            tile3<false>(Kb, Vb, pbB, qB0, qB1, ones, m, quad, sw, kh, kvb, qcB, oB, laB);
        else
            tile3<true >(Kb, Vb, pbB, qB0, qB1, ones, m, quad, sw, kh, kvb, qcB, oB, laB);
    }

    // l_q already fully reduced over this wave's kv-half (MFMA k-reduction):
    // every lane holds l for q=lane&15 in every lacc reg.
    float lA = laA[0];
    float lB = laB[0];

    // cross-kh combine: kh=1 writes O-partials + l, kh=0 merges & stores
    __syncthreads();
    f32x4* ob = (f32x4*)smem;                 // 32KB overlay on K+V dbuf
    float* lb = (float*)&smem[26624];         // 128 floats
    if (kh) {
        f32x4* dst = ob + (size_t)iq * 512 + lane;
#pragma unroll
        for (int dg = 0; dg < 4; ++dg) {
            dst[dg * 64] = oA[dg];
            dst[(4 + dg) * 64] = oB[dg];
        }
        if (quad == 0) {
            lb[(iq * 2 + 0) * 16 + m] = lA;
            lb[(iq * 2 + 1) * 16 + m] = lB;
        }
    }
    __syncthreads();
    if (!kh) {
        f32x4* src = ob + (size_t)iq * 512 + lane;
#pragma unroll
        for (int dg = 0; dg < 4; ++dg) {
            oA[dg] += src[dg * 64];
            oB[dg] += src[(4 + dg) * 64];
        }
        lA += lb[(iq * 2 + 0) * 16 + m];
        lB += lb[(iq * 2 + 1) * 16 + m];
        float invA = 1.0f / lA, invB = 1.0f / lB;

        int b = head >> 4, h = head & 15;
        size_t roA = ((size_t)(b * TT + rbA + m)) * CCH + h * HDD;
        size_t roB = ((size_t)(b * TT + rbB + m)) * CCH + h * HDD;
#pragma unroll
        for (int dg = 0; dg < 4; ++dg) {
            uint2 ov;
            ov.x = pk_bf16(oA[dg][0] * invA, oA[dg][1] * invA);
            ov.y = pk_bf16(oA[dg][2] * invA, oA[dg][3] * invA);
            *(uint2*)&Y[roA + dg * 16 + quad * 4] = ov;
            ov.x = pk_bf16(oB[dg][0] * invB, oB[dg][1] * invB);
            ov.y = pk_bf16(oB[dg][2] * invB, oB[dg][3] * invB);
            *(uint2*)&Y[roB + dg * 16 + quad * 4] = ov;
        }
    }
}

// ---------------- launch ----------------

extern "C" void kernel_launch(void* const* d_in, const int* in_sizes, int n_in,
                              void* d_out, int out_size, void* d_ws, size_t ws_size,
                              hipStream_t stream) {
    const float* x      = (const float*)d_in[0];
    const float* w_attn = (const float*)d_in[1];
    const float* w_proj = (const float*)d_in[2];
    float* out = (float*)d_out;

    char* ws = (char*)d_ws;
    u16* x_bf   = (u16*)ws; ws += (size_t)M_TOK * CCH * 2;         // 8 MB
    u16* wqkvT  = (u16*)ws; ws += (size_t)N_QKV * CCH * 2;         // 6 MB
    u16* wprojT = (u16*)ws; ws += (size_t)CCH * CCH * 2;           // 2 MB
    u16* qbuf   = (u16*)ws; ws += (size_t)BB * NHH * TT * HDD * 2; // 8 MB
    u16* kbuf   = (u16*)ws; ws += (size_t)BB * NHH * TT * HDD * 2; // 8 MB
    u16* vtb    = (u16*)ws; ws += (size_t)BB * NHH * HDD * TT * 2; // 8 MB
    u16* yb     = (u16*)ws; ws += (size_t)M_TOK * CCH * 2;         // 8 MB

    // one-time: allow big dynamic LDS for the pipelined GEMMs (host-side)
    static bool attr_done = false;
    if (!attr_done) {
        (void)hipFuncSetAttribute(reinterpret_cast<const void*>(qkv_gemm_kernel),
                                  hipFuncAttributeMaxDynamicSharedMemorySize,
                                  QKV_SMEM_BYTES);
        (void)hipFuncSetAttribute(reinterpret_cast<const void*>(proj_gemm_kernel),
                                  hipFuncAttributeMaxDynamicSharedMemorySize,
                                  PRJ_SMEM_BYTES);
        attr_done = true;
    }

    // softmax scale * log2(e), folded into Q columns of w_attn during transpose
    const float QSC = 0.125f * 1.44269504088896f;

    // 1. cast x -> bf16
    cast_bf16_kernel<<<dim3(M_TOK * CCH / 4 / 256), dim3(256), 0, stream>>>(x, x_bf, M_TOK * CCH / 4);
    // 2. transpose weights -> bf16 [N][K]
    transpose_bf16_kernel<<<dim3(N_QKV / 32, CCH / 32), dim3(32, 8), 0, stream>>>(
        w_attn, wqkvT, CCH, N_QKV, CCH, QSC);
    transpose_bf16_kernel<<<dim3(CCH / 32, CCH / 32), dim3(32, 8), 0, stream>>>(
        w_proj, wprojT, CCH, CCH, 0, 1.0f);
    // 3. QKV GEMM v2: 256 blocks (1/CU), 256x192 tiles, counted-vmcnt pipeline
    qkv_gemm_kernel<<<dim3(16, 16), dim3(512), QKV_SMEM_BYTES, stream>>>(
        x_bf, wqkvT, qbuf, kbuf, vtb);
    // 4. flash attention v15b (unchanged)
    attn_kernel<<<dim3(512), dim3(512), 0, stream>>>(qbuf, kbuf, vtb, yb);
    // 5. proj GEMM v2: 256 blocks (1/CU), 128x128 tiles, counted-vmcnt pipeline
    proj_gemm_kernel<<<dim3(8, 32), dim3(512), PRJ_SMEM_BYTES, stream>>>(
        yb, wprojT, out);
}